// Round 1
// baseline (685.190 us; speedup 1.0000x reference)
//
#include <hip/hip_runtime.h>
#include <stdint.h>

typedef __attribute__((ext_vector_type(8))) short short8;
typedef __attribute__((ext_vector_type(4))) float f32x4;

__device__ __forceinline__ unsigned short f2bf(float x) {
  unsigned int u = __float_as_uint(x);
  u += 0x7fffu + ((u >> 16) & 1u);
  return (unsigned short)(u >> 16);
}
__device__ __forceinline__ float bf2f(unsigned short h) {
  return __uint_as_float(((unsigned int)h) << 16);
}

// ---------- split fp32 -> (hi, lo) bf16, 4 elems/thread ----------
__global__ __launch_bounds__(256) void split_pair_kernel(
    const float* __restrict__ in, unsigned short* __restrict__ h,
    unsigned short* __restrict__ l) {
  size_t i = (size_t)blockIdx.x * 256 + threadIdx.x;
  float4 v = ((const float4*)in)[i];
  unsigned short h0 = f2bf(v.x), h1 = f2bf(v.y), h2 = f2bf(v.z), h3 = f2bf(v.w);
  ((ushort4*)h)[i] = make_ushort4(h0, h1, h2, h3);
  ((ushort4*)l)[i] = make_ushort4(f2bf(v.x - bf2f(h0)), f2bf(v.y - bf2f(h1)),
                                  f2bf(v.z - bf2f(h2)), f2bf(v.w - bf2f(h3)));
}

// ---------- transpose W [K][N] fp32 -> hi/lo bf16 [N][K] ----------
__global__ __launch_bounds__(256) void transpose_split_kernel(
    const float* __restrict__ W, unsigned short* __restrict__ hT,
    unsigned short* __restrict__ lT, int Kd, int Nd) {
  __shared__ float tile[32][33];
  int r = threadIdx.x >> 3;
  int c = (threadIdx.x & 7) * 4;
  int k0 = blockIdx.y * 32, n0 = blockIdx.x * 32;
  float4 v = *(const float4*)&W[(size_t)(k0 + r) * Nd + n0 + c];
  tile[r][c] = v.x; tile[r][c + 1] = v.y; tile[r][c + 2] = v.z; tile[r][c + 3] = v.w;
  __syncthreads();
  float x0 = tile[c + 0][r], x1 = tile[c + 1][r], x2 = tile[c + 2][r], x3 = tile[c + 3][r];
  unsigned short h0 = f2bf(x0), h1 = f2bf(x1), h2 = f2bf(x2), h3 = f2bf(x3);
  size_t o = (size_t)(n0 + r) * Kd + k0 + c;
  *(ushort4*)&hT[o] = make_ushort4(h0, h1, h2, h3);
  *(ushort4*)&lT[o] = make_ushort4(f2bf(x0 - bf2f(h0)), f2bf(x1 - bf2f(h1)),
                                   f2bf(x2 - bf2f(h2)), f2bf(x3 - bf2f(h3)));
}

// ---------- generic NT MFMA GEMM: C[M][N] = A[M][K] * B[N][K]^T ----------
// NT=3: split hi/lo 3-term (Ah*Bh + Ah*Bl + Al*Bh) for ~fp32 precision.
// OMODE: 0 = fp32 [row*ldo+col]; 1 = hi/lo bf16 pair; 2 = bf16 transposed [col*ldo+row]
constexpr int BM = 128, BN = 128, BKT = 32, RS = 56;  // RS: padded LDS row stride (elems)

template <int NT, int OMODE>
__global__ __launch_bounds__(256) void gemm_nt_kernel(
    const unsigned short* __restrict__ Ah, const unsigned short* __restrict__ Al,
    const unsigned short* __restrict__ Bh, const unsigned short* __restrict__ Bl,
    const float* __restrict__ bias, void* __restrict__ out0,
    void* __restrict__ out1, int K, int lda, int ldb, int ldo) {
  __shared__ unsigned short sAh[BM * RS];
  __shared__ unsigned short sBh[BN * RS];
  __shared__ unsigned short sAl[NT == 3 ? BM * RS : 8];
  __shared__ unsigned short sBl[NT == 3 ? BN * RS : 8];

  const int t = threadIdx.x;
  const int m0 = blockIdx.y * BM;
  const int n0 = blockIdx.x * BN;
  const int wid = t >> 6;
  const int lane = t & 63;
  const int wm = (wid >> 1) * 64;   // 2x2 waves, 64x64 each
  const int wn = (wid & 1) * 64;
  const int lr = lane & 15;         // fragment 16-index
  const int lk = (lane >> 4) * 8;   // fragment k offset (8 consecutive bf16)

  const int sr = t >> 2;            // staging row (0..63 per pass)
  const int sc = (t & 3) * 8;       // staging col (elems)

  f32x4 acc[4][4] = {};

  for (int k0 = 0; k0 < K; k0 += BKT) {
#pragma unroll
    for (int p = 0; p < 2; ++p) {
      int row = p * 64 + sr;
      *(uint4*)&sAh[row * RS + sc] = *(const uint4*)&Ah[(size_t)(m0 + row) * lda + k0 + sc];
      *(uint4*)&sBh[row * RS + sc] = *(const uint4*)&Bh[(size_t)(n0 + row) * ldb + k0 + sc];
      if constexpr (NT == 3) {
        *(uint4*)&sAl[row * RS + sc] = *(const uint4*)&Al[(size_t)(m0 + row) * lda + k0 + sc];
        *(uint4*)&sBl[row * RS + sc] = *(const uint4*)&Bl[(size_t)(n0 + row) * ldb + k0 + sc];
      }
    }
    __syncthreads();
    short8 ah[4], bh[4], al[4], bl[4];
#pragma unroll
    for (int m = 0; m < 4; ++m) {
      ah[m] = *(const short8*)&sAh[(wm + m * 16 + lr) * RS + lk];
      bh[m] = *(const short8*)&sBh[(wn + m * 16 + lr) * RS + lk];
      if constexpr (NT == 3) {
        al[m] = *(const short8*)&sAl[(wm + m * 16 + lr) * RS + lk];
        bl[m] = *(const short8*)&sBl[(wn + m * 16 + lr) * RS + lk];
      }
    }
#pragma unroll
    for (int m = 0; m < 4; ++m)
#pragma unroll
      for (int n = 0; n < 4; ++n) {
        acc[m][n] = __builtin_amdgcn_mfma_f32_16x16x32_bf16(ah[m], bh[n], acc[m][n], 0, 0, 0);
        if constexpr (NT == 3) {
          acc[m][n] = __builtin_amdgcn_mfma_f32_16x16x32_bf16(ah[m], bl[n], acc[m][n], 0, 0, 0);
          acc[m][n] = __builtin_amdgcn_mfma_f32_16x16x32_bf16(al[m], bh[n], acc[m][n], 0, 0, 0);
        }
      }
    __syncthreads();
  }

  const int or0 = (lane >> 4) * 4;  // C/D: row=(lane>>4)*4+r, col=lane&15 (m89)
#pragma unroll
  for (int m = 0; m < 4; ++m)
#pragma unroll
    for (int n = 0; n < 4; ++n)
#pragma unroll
      for (int r = 0; r < 4; ++r) {
        int row = m0 + wm + m * 16 + or0 + r;
        int col = n0 + wn + n * 16 + lr;
        float x = acc[m][n][r];
        if (bias) x += bias[col];
        if constexpr (OMODE == 0) {
          ((float*)out0)[(size_t)row * ldo + col] = x;
        } else if constexpr (OMODE == 1) {
          unsigned short h = f2bf(x);
          ((unsigned short*)out0)[(size_t)row * ldo + col] = h;
          ((unsigned short*)out1)[(size_t)row * ldo + col] = f2bf(x - bf2f(h));
        } else {
          ((unsigned short*)out0)[(size_t)col * ldo + row] = f2bf(x);
        }
      }
}

// ---------- row softmax: fp32 [4096] -> bf16 probs ----------
__global__ __launch_bounds__(256) void softmax_rows_kernel(
    const float* __restrict__ Sm, unsigned short* __restrict__ P, int ncol) {
  const int t = threadIdx.x;
  const float* srow = Sm + (size_t)blockIdx.x * ncol;
  float4 v[4];
  float m = -3.4e38f;
#pragma unroll
  for (int i = 0; i < 4; ++i) {
    v[i] = ((const float4*)srow)[t + 256 * i];
    m = fmaxf(m, fmaxf(fmaxf(v[i].x, v[i].y), fmaxf(v[i].z, v[i].w)));
  }
#pragma unroll
  for (int off = 32; off >= 1; off >>= 1) m = fmaxf(m, __shfl_down(m, off));
  __shared__ float redm[4];
  if ((t & 63) == 0) redm[t >> 6] = m;
  __syncthreads();
  m = fmaxf(fmaxf(redm[0], redm[1]), fmaxf(redm[2], redm[3]));
  float s = 0.f;
#pragma unroll
  for (int i = 0; i < 4; ++i) {
    v[i].x = __expf(v[i].x - m);
    v[i].y = __expf(v[i].y - m);
    v[i].z = __expf(v[i].z - m);
    v[i].w = __expf(v[i].w - m);
    s += v[i].x + v[i].y + v[i].z + v[i].w;
  }
#pragma unroll
  for (int off = 32; off >= 1; off >>= 1) s += __shfl_down(s, off);
  __shared__ float reds[4];
  if ((t & 63) == 0) reds[t >> 6] = s;
  __syncthreads();
  s = reds[0] + reds[1] + reds[2] + reds[3];
  float inv = 1.f / s;
  unsigned short* prow = P + (size_t)blockIdx.x * ncol;
#pragma unroll
  for (int i = 0; i < 4; ++i) {
    ushort4 o = make_ushort4(f2bf(v[i].x * inv), f2bf(v[i].y * inv),
                             f2bf(v[i].z * inv), f2bf(v[i].w * inv));
    ((ushort4*)prow)[t + 256 * i] = o;
  }
}

extern "C" void kernel_launch(void* const* d_in, const int* in_sizes, int n_in,
                              void* d_out, int out_size, void* d_ws, size_t ws_size,
                              hipStream_t stream) {
  const float* hs = (const float*)d_in[0];
  const float* Wq = (const float*)d_in[1];
  const float* bq = (const float*)d_in[2];
  const float* Wk = (const float*)d_in[3];
  const float* bk = (const float*)d_in[4];
  const float* Wv = (const float*)d_in[5];
  const float* bv = (const float*)d_in[6];
  float* out = (float*)d_out;

  constexpr int Bb = 2, Ss = 4096, Hh = 1024;
  constexpr int Mm = Bb * Ss;  // 8192 tokens
  char* ws = (char*)d_ws;

  // ---- workspace layout (needs ~184.6 MB) ----
  // Region A (dead after projections), overlapped by region C afterwards:
  const size_t szSplit = (size_t)Mm * Hh * 2;  // 16 MB
  const size_t szW = (size_t)Hh * Hh * 2;      // 2 MB
  unsigned short* hs_h = (unsigned short*)(ws + 0);
  unsigned short* hs_l = (unsigned short*)(ws + szSplit);
  unsigned short* WqhT = (unsigned short*)(ws + 2 * szSplit + 0 * szW);
  unsigned short* WqlT = (unsigned short*)(ws + 2 * szSplit + 1 * szW);
  unsigned short* WkhT = (unsigned short*)(ws + 2 * szSplit + 2 * szW);
  unsigned short* WklT = (unsigned short*)(ws + 2 * szSplit + 3 * szW);
  unsigned short* WvhT = (unsigned short*)(ws + 2 * szSplit + 4 * szW);
  unsigned short* WvlT = (unsigned short*)(ws + 2 * szSplit + 5 * szW);
  // Region C (scores + probs), reused per batch, overlaps dead region A:
  float* Sbuf = (float*)(ws + 0);                       // 67.1 MB
  unsigned short* Pbuf = (unsigned short*)(ws + (size_t)Ss * Ss * 4);  // 33.5 MB
  // Region B (live to the end):
  char* bbase = ws + (size_t)Ss * Ss * 4 + (size_t)Ss * Ss * 2;  // 100.66 MB
  unsigned short* qh = (unsigned short*)(bbase + 0 * szSplit);
  unsigned short* ql = (unsigned short*)(bbase + 1 * szSplit);
  unsigned short* kh = (unsigned short*)(bbase + 2 * szSplit);
  unsigned short* kl = (unsigned short*)(bbase + 3 * szSplit);
  unsigned short* vT = (unsigned short*)(bbase + 4 * szSplit);  // [H][Mm] bf16

  // 1) split inputs
  split_pair_kernel<<<dim3(Mm * Hh / 1024), 256, 0, stream>>>(hs, hs_h, hs_l);
  transpose_split_kernel<<<dim3(Hh / 32, Hh / 32), 256, 0, stream>>>(Wq, WqhT, WqlT, Hh, Hh);
  transpose_split_kernel<<<dim3(Hh / 32, Hh / 32), 256, 0, stream>>>(Wk, WkhT, WklT, Hh, Hh);
  transpose_split_kernel<<<dim3(Hh / 32, Hh / 32), 256, 0, stream>>>(Wv, WvhT, WvlT, Hh, Hh);

  // 2) projections (split 3-term): q,k -> hi/lo pairs; v -> transposed bf16
  gemm_nt_kernel<3, 1><<<dim3(Hh / BN, Mm / BM), 256, 0, stream>>>(
      hs_h, hs_l, WqhT, WqlT, bq, qh, ql, Hh, Hh, Hh, Hh);
  gemm_nt_kernel<3, 1><<<dim3(Hh / BN, Mm / BM), 256, 0, stream>>>(
      hs_h, hs_l, WkhT, WklT, bk, kh, kl, Hh, Hh, Hh, Hh);
  gemm_nt_kernel<3, 2><<<dim3(Hh / BN, Mm / BM), 256, 0, stream>>>(
      hs_h, hs_l, WvhT, WvlT, bv, vT, nullptr, Hh, Hh, Hh, Mm);

  // 3) per batch: scores -> softmax -> context
  for (int b = 0; b < Bb; ++b) {
    const size_t tok = (size_t)b * Ss * Hh;
    gemm_nt_kernel<3, 0><<<dim3(Ss / BN, Ss / BM), 256, 0, stream>>>(
        qh + tok, ql + tok, kh + tok, kl + tok, nullptr, Sbuf, nullptr, Hh, Hh, Hh, Ss);
    softmax_rows_kernel<<<dim3(Ss), 256, 0, stream>>>(Sbuf, Pbuf, Ss);
    gemm_nt_kernel<1, 0><<<dim3(Hh / BN, Ss / BM), 256, 0, stream>>>(
        Pbuf, nullptr, vT + (size_t)b * Ss, nullptr, nullptr,
        out + tok, nullptr, Ss, Ss, Mm, Hh);
  }
}

// Round 2
// 654.115 us; speedup vs baseline: 1.0475x; 1.0475x over previous
//
#include <hip/hip_runtime.h>
#include <stdint.h>

typedef __attribute__((ext_vector_type(8))) short short8;
typedef __attribute__((ext_vector_type(4))) float f32x4;

__device__ __forceinline__ unsigned short f2bf(float x) {
  unsigned int u = __float_as_uint(x);
  u += 0x7fffu + ((u >> 16) & 1u);
  return (unsigned short)(u >> 16);
}
__device__ __forceinline__ float bf2f(unsigned short h) {
  return __uint_as_float(((unsigned int)h) << 16);
}

#define GLOAD16(gsrc, ldst)                                              \
  __builtin_amdgcn_global_load_lds(                                      \
      (const __attribute__((address_space(1))) void*)(gsrc),             \
      (__attribute__((address_space(3))) void*)(ldst), 16, 0, 0)

// ---------- split fp32 -> (hi, lo) bf16, 4 elems/thread ----------
__global__ __launch_bounds__(256) void split_pair_kernel(
    const float* __restrict__ in, unsigned short* __restrict__ h,
    unsigned short* __restrict__ l) {
  size_t i = (size_t)blockIdx.x * 256 + threadIdx.x;
  float4 v = ((const float4*)in)[i];
  unsigned short h0 = f2bf(v.x), h1 = f2bf(v.y), h2 = f2bf(v.z), h3 = f2bf(v.w);
  ((ushort4*)h)[i] = make_ushort4(h0, h1, h2, h3);
  ((ushort4*)l)[i] = make_ushort4(f2bf(v.x - bf2f(h0)), f2bf(v.y - bf2f(h1)),
                                  f2bf(v.z - bf2f(h2)), f2bf(v.w - bf2f(h3)));
}

// ---------- transpose W [K][N] fp32 -> hi/lo bf16 [N][K] ----------
__global__ __launch_bounds__(256) void transpose_split_kernel(
    const float* __restrict__ W, unsigned short* __restrict__ hT,
    unsigned short* __restrict__ lT, int Kd, int Nd) {
  __shared__ float tile[32][33];
  int r = threadIdx.x >> 3;
  int c = (threadIdx.x & 7) * 4;
  int k0 = blockIdx.y * 32, n0 = blockIdx.x * 32;
  float4 v = *(const float4*)&W[(size_t)(k0 + r) * Nd + n0 + c];
  tile[r][c] = v.x; tile[r][c + 1] = v.y; tile[r][c + 2] = v.z; tile[r][c + 3] = v.w;
  __syncthreads();
  float x0 = tile[c + 0][r], x1 = tile[c + 1][r], x2 = tile[c + 2][r], x3 = tile[c + 3][r];
  unsigned short h0 = f2bf(x0), h1 = f2bf(x1), h2 = f2bf(x2), h3 = f2bf(x3);
  size_t o = (size_t)(n0 + r) * Kd + k0 + c;
  *(ushort4*)&hT[o] = make_ushort4(h0, h1, h2, h3);
  *(ushort4*)&lT[o] = make_ushort4(f2bf(x0 - bf2f(h0)), f2bf(x1 - bf2f(h1)),
                                   f2bf(x2 - bf2f(h2)), f2bf(x3 - bf2f(h3)));
}

// =====================================================================
// Deep-pipelined 3-term split-bf16 NT GEMM: C[M][N] = A*B^T (A=Ah+Al, B=Bh+Bl)
// 256x128 tile, BK=32, 8 waves (2M x 4N), 3-deep LDS buffers (144 KB),
// fragment-linear LDS subtiles (16x32 = 1KB, lane l owns bytes [16l,16l+16)),
// staged via global_load_lds w/ per-lane source addresses, counted vmcnt(6).
// OMODE: 0 = fp32 [row*ldo+col]; 1 = hi/lo bf16 pair; 2 = bf16 transposed.
// =====================================================================
template <int OMODE>
__global__ __launch_bounds__(512, 2) void gemm3_kernel(
    const unsigned short* __restrict__ Ah, const unsigned short* __restrict__ Al,
    const unsigned short* __restrict__ Bh, const unsigned short* __restrict__ Bl,
    const float* __restrict__ bias, void* __restrict__ out0,
    void* __restrict__ out1, int K, int lda, int ldb, int ldo) {
  // per K-step buffer: [A0h:16][A1l:16][B0h:8][B1l:8] subtiles of 1024B = 48KB
  __shared__ __align__(16) char smem[3 * 48 * 1024];

  const int t = threadIdx.x;
  const int wid = t >> 6;
  const int lane = t & 63;
  const int waveM = wid >> 2;   // 0..1 -> 128-row half
  const int waveN = wid & 3;    // 0..3 -> 32-col quarter
  const int lr0 = lane & 15;
  const int lk0 = (lane >> 4) * 8;
  const int m0 = blockIdx.y * 256;
  const int n0 = blockIdx.x * 128;

  // precompute the 6 per-wave staging source pointers (at k = 0)
  const unsigned short* slot_src[6];
#pragma unroll
  for (int s = 0; s < 6; ++s) {
    int si = 6 * wid + s;
    const unsigned short* base;
    size_t roff;
    if (si < 16)      { base = Ah; roff = (size_t)(m0 + si * 16 + lr0) * lda; }
    else if (si < 32) { base = Al; roff = (size_t)(m0 + (si - 16) * 16 + lr0) * lda; }
    else if (si < 40) { base = Bh; roff = (size_t)(n0 + (si - 32) * 16 + lr0) * ldb; }
    else              { base = Bl; roff = (size_t)(n0 + (si - 40) * 16 + lr0) * ldb; }
    slot_src[s] = base + roff + lk0;
  }

  const int NTILES = K >> 5;  // K / 32
  f32x4 acc[8][2] = {};

  // prologue: stage tiles 0 and 1
#pragma unroll
  for (int tt = 0; tt < 2; ++tt)
#pragma unroll
    for (int s = 0; s < 6; ++s)
      GLOAD16(slot_src[s] + (size_t)tt * 32,
              smem + tt * 49152 + (6 * wid + s) * 1024);
  asm volatile("s_waitcnt vmcnt(6)" ::: "memory");
  __builtin_amdgcn_s_barrier();
  __builtin_amdgcn_sched_barrier(0);

  for (int tile = 0; tile < NTILES; ++tile) {
    const int cur = tile % 3;
    const int nxt = (tile + 2) % 3;
    const bool do_stage = (tile + 2) < NTILES;
    const char* cb = smem + cur * 49152;
    char* nb = smem + nxt * 49152;
    short8 b0f[2], b1f[2];
#pragma unroll
    for (int p = 0; p < 4; ++p) {
      short8 a0f[2], a1f[2];
#pragma unroll
      for (int i = 0; i < 2; ++i) {
        int mg = waveM * 8 + 2 * p + i;
        a0f[i] = *(const short8*)(cb + mg * 1024 + lane * 16);
        a1f[i] = *(const short8*)(cb + (16 + mg) * 1024 + lane * 16);
      }
      if (p == 0) {
#pragma unroll
        for (int j = 0; j < 2; ++j) {
          int ng = waveN * 2 + j;
          b0f[j] = *(const short8*)(cb + (32 + ng) * 1024 + lane * 16);
          b1f[j] = *(const short8*)(cb + (40 + ng) * 1024 + lane * 16);
        }
      }
      if (do_stage && p < 3) {
#pragma unroll
        for (int s = 0; s < 2; ++s) {
          int slot = 2 * p + s;
          GLOAD16(slot_src[slot] + (size_t)(tile + 2) * 32,
                  nb + (6 * wid + slot) * 1024);
        }
      }
      __builtin_amdgcn_s_setprio(1);
#pragma unroll
      for (int i = 0; i < 2; ++i)
#pragma unroll
        for (int j = 0; j < 2; ++j) {
          f32x4 c = acc[2 * p + i][j];
          c = __builtin_amdgcn_mfma_f32_16x16x32_bf16(a0f[i], b0f[j], c, 0, 0, 0);
          c = __builtin_amdgcn_mfma_f32_16x16x32_bf16(a0f[i], b1f[j], c, 0, 0, 0);
          c = __builtin_amdgcn_mfma_f32_16x16x32_bf16(a1f[i], b0f[j], c, 0, 0, 0);
          acc[2 * p + i][j] = c;
        }
      __builtin_amdgcn_s_setprio(0);
      if (p < 3) __builtin_amdgcn_s_barrier();
    }
    if (tile + 1 < NTILES) {
      if (do_stage) asm volatile("s_waitcnt vmcnt(6)" ::: "memory");
      else          asm volatile("s_waitcnt vmcnt(0)" ::: "memory");
      __builtin_amdgcn_s_barrier();
      __builtin_amdgcn_sched_barrier(0);
    }
  }

  // epilogue: C/D layout col=lane&15, row=(lane>>4)*4+r
  const int or0 = (lane >> 4) * 4;
#pragma unroll
  for (int mm = 0; mm < 8; ++mm)
#pragma unroll
    for (int j = 0; j < 2; ++j)
#pragma unroll
      for (int r = 0; r < 4; ++r) {
        int row = m0 + waveM * 128 + mm * 16 + or0 + r;
        int col = n0 + waveN * 32 + j * 16 + lr0;
        float x = acc[mm][j][r];
        if (bias) x += bias[col];
        if constexpr (OMODE == 0) {
          ((float*)out0)[(size_t)row * ldo + col] = x;
        } else if constexpr (OMODE == 1) {
          unsigned short h = f2bf(x);
          ((unsigned short*)out0)[(size_t)row * ldo + col] = h;
          ((unsigned short*)out1)[(size_t)row * ldo + col] = f2bf(x - bf2f(h));
        } else {
          ((unsigned short*)out0)[(size_t)col * ldo + row] = f2bf(x);
        }
      }
}

// ---------- old 128x128 NT GEMM (kept for PV: NT=1, fp32 out) ----------
constexpr int BM = 128, BN = 128, BKT = 32, RS = 56;

template <int NT, int OMODE>
__global__ __launch_bounds__(256) void gemm_nt_kernel(
    const unsigned short* __restrict__ Ah, const unsigned short* __restrict__ Al,
    const unsigned short* __restrict__ Bh, const unsigned short* __restrict__ Bl,
    const float* __restrict__ bias, void* __restrict__ out0,
    void* __restrict__ out1, int K, int lda, int ldb, int ldo) {
  __shared__ unsigned short sAh[BM * RS];
  __shared__ unsigned short sBh[BN * RS];
  __shared__ unsigned short sAl[NT == 3 ? BM * RS : 8];
  __shared__ unsigned short sBl[NT == 3 ? BN * RS : 8];

  const int t = threadIdx.x;
  const int m0 = blockIdx.y * BM;
  const int n0 = blockIdx.x * BN;
  const int wid = t >> 6;
  const int lane = t & 63;
  const int wm = (wid >> 1) * 64;
  const int wn = (wid & 1) * 64;
  const int lr = lane & 15;
  const int lk = (lane >> 4) * 8;
  const int sr = t >> 2;
  const int sc = (t & 3) * 8;

  f32x4 acc[4][4] = {};

  for (int k0 = 0; k0 < K; k0 += BKT) {
#pragma unroll
    for (int p = 0; p < 2; ++p) {
      int row = p * 64 + sr;
      *(uint4*)&sAh[row * RS + sc] = *(const uint4*)&Ah[(size_t)(m0 + row) * lda + k0 + sc];
      *(uint4*)&sBh[row * RS + sc] = *(const uint4*)&Bh[(size_t)(n0 + row) * ldb + k0 + sc];
      if constexpr (NT == 3) {
        *(uint4*)&sAl[row * RS + sc] = *(const uint4*)&Al[(size_t)(m0 + row) * lda + k0 + sc];
        *(uint4*)&sBl[row * RS + sc] = *(const uint4*)&Bl[(size_t)(n0 + row) * ldb + k0 + sc];
      }
    }
    __syncthreads();
    short8 ah[4], bh[4], al[4], bl[4];
#pragma unroll
    for (int m = 0; m < 4; ++m) {
      ah[m] = *(const short8*)&sAh[(wm + m * 16 + lr) * RS + lk];
      bh[m] = *(const short8*)&sBh[(wn + m * 16 + lr) * RS + lk];
      if constexpr (NT == 3) {
        al[m] = *(const short8*)&sAl[(wm + m * 16 + lr) * RS + lk];
        bl[m] = *(const short8*)&sBl[(wn + m * 16 + lr) * RS + lk];
      }
    }
#pragma unroll
    for (int m = 0; m < 4; ++m)
#pragma unroll
      for (int n = 0; n < 4; ++n) {
        acc[m][n] = __builtin_amdgcn_mfma_f32_16x16x32_bf16(ah[m], bh[n], acc[m][n], 0, 0, 0);
        if constexpr (NT == 3) {
          acc[m][n] = __builtin_amdgcn_mfma_f32_16x16x32_bf16(ah[m], bl[n], acc[m][n], 0, 0, 0);
          acc[m][n] = __builtin_amdgcn_mfma_f32_16x16x32_bf16(al[m], bh[n], acc[m][n], 0, 0, 0);
        }
      }
    __syncthreads();
  }

  const int or0 = (lane >> 4) * 4;
#pragma unroll
  for (int m = 0; m < 4; ++m)
#pragma unroll
    for (int n = 0; n < 4; ++n)
#pragma unroll
      for (int r = 0; r < 4; ++r) {
        int row = m0 + wm + m * 16 + or0 + r;
        int col = n0 + wn + n * 16 + lr;
        float x = acc[m][n][r];
        if (bias) x += bias[col];
        if constexpr (OMODE == 0) {
          ((float*)out0)[(size_t)row * ldo + col] = x;
        } else if constexpr (OMODE == 1) {
          unsigned short h = f2bf(x);
          ((unsigned short*)out0)[(size_t)row * ldo + col] = h;
          ((unsigned short*)out1)[(size_t)row * ldo + col] = f2bf(x - bf2f(h));
        } else {
          ((unsigned short*)out0)[(size_t)col * ldo + row] = f2bf(x);
        }
      }
}

// ---------- row softmax: fp32 [4096] -> bf16 probs ----------
__global__ __launch_bounds__(256) void softmax_rows_kernel(
    const float* __restrict__ Sm, unsigned short* __restrict__ P, int ncol) {
  const int t = threadIdx.x;
  const float* srow = Sm + (size_t)blockIdx.x * ncol;
  float4 v[4];
  float m = -3.4e38f;
#pragma unroll
  for (int i = 0; i < 4; ++i) {
    v[i] = ((const float4*)srow)[t + 256 * i];
    m = fmaxf(m, fmaxf(fmaxf(v[i].x, v[i].y), fmaxf(v[i].z, v[i].w)));
  }
#pragma unroll
  for (int off = 32; off >= 1; off >>= 1) m = fmaxf(m, __shfl_down(m, off));
  __shared__ float redm[4];
  if ((t & 63) == 0) redm[t >> 6] = m;
  __syncthreads();
  m = fmaxf(fmaxf(redm[0], redm[1]), fmaxf(redm[2], redm[3]));
  float s = 0.f;
#pragma unroll
  for (int i = 0; i < 4; ++i) {
    v[i].x = __expf(v[i].x - m);
    v[i].y = __expf(v[i].y - m);
    v[i].z = __expf(v[i].z - m);
    v[i].w = __expf(v[i].w - m);
    s += v[i].x + v[i].y + v[i].z + v[i].w;
  }
#pragma unroll
  for (int off = 32; off >= 1; off >>= 1) s += __shfl_down(s, off);
  __shared__ float reds[4];
  if ((t & 63) == 0) reds[t >> 6] = s;
  __syncthreads();
  s = reds[0] + reds[1] + reds[2] + reds[3];
  float inv = 1.f / s;
  unsigned short* prow = P + (size_t)blockIdx.x * ncol;
#pragma unroll
  for (int i = 0; i < 4; ++i) {
    ushort4 o = make_ushort4(f2bf(v[i].x * inv), f2bf(v[i].y * inv),
                             f2bf(v[i].z * inv), f2bf(v[i].w * inv));
    ((ushort4*)prow)[t + 256 * i] = o;
  }
}

extern "C" void kernel_launch(void* const* d_in, const int* in_sizes, int n_in,
                              void* d_out, int out_size, void* d_ws, size_t ws_size,
                              hipStream_t stream) {
  const float* hs = (const float*)d_in[0];
  const float* Wq = (const float*)d_in[1];
  const float* bq = (const float*)d_in[2];
  const float* Wk = (const float*)d_in[3];
  const float* bk = (const float*)d_in[4];
  const float* Wv = (const float*)d_in[5];
  const float* bv = (const float*)d_in[6];
  float* out = (float*)d_out;

  constexpr int Bb = 2, Ss = 4096, Hh = 1024;
  constexpr int Mm = Bb * Ss;
  char* ws = (char*)d_ws;

  const size_t szSplit = (size_t)Mm * Hh * 2;  // 16 MB
  const size_t szW = (size_t)Hh * Hh * 2;      // 2 MB
  unsigned short* hs_h = (unsigned short*)(ws + 0);
  unsigned short* hs_l = (unsigned short*)(ws + szSplit);
  unsigned short* WqhT = (unsigned short*)(ws + 2 * szSplit + 0 * szW);
  unsigned short* WqlT = (unsigned short*)(ws + 2 * szSplit + 1 * szW);
  unsigned short* WkhT = (unsigned short*)(ws + 2 * szSplit + 2 * szW);
  unsigned short* WklT = (unsigned short*)(ws + 2 * szSplit + 3 * szW);
  unsigned short* WvhT = (unsigned short*)(ws + 2 * szSplit + 4 * szW);
  unsigned short* WvlT = (unsigned short*)(ws + 2 * szSplit + 5 * szW);
  float* Sbuf = (float*)(ws + 0);
  unsigned short* Pbuf = (unsigned short*)(ws + (size_t)Ss * Ss * 4);
  char* bbase = ws + (size_t)Ss * Ss * 4 + (size_t)Ss * Ss * 2;
  unsigned short* qh = (unsigned short*)(bbase + 0 * szSplit);
  unsigned short* ql = (unsigned short*)(bbase + 1 * szSplit);
  unsigned short* kh = (unsigned short*)(bbase + 2 * szSplit);
  unsigned short* kl = (unsigned short*)(bbase + 3 * szSplit);
  unsigned short* vT = (unsigned short*)(bbase + 4 * szSplit);  // [H][Mm] bf16

  // 1) split inputs
  split_pair_kernel<<<dim3(Mm * Hh / 1024), 256, 0, stream>>>(hs, hs_h, hs_l);
  transpose_split_kernel<<<dim3(Hh / 32, Hh / 32), 256, 0, stream>>>(Wq, WqhT, WqlT, Hh, Hh);
  transpose_split_kernel<<<dim3(Hh / 32, Hh / 32), 256, 0, stream>>>(Wk, WkhT, WklT, Hh, Hh);
  transpose_split_kernel<<<dim3(Hh / 32, Hh / 32), 256, 0, stream>>>(Wv, WvhT, WvlT, Hh, Hh);

  // 2) projections (pipelined 3-term): q,k -> hi/lo pairs; v -> transposed bf16
  gemm3_kernel<1><<<dim3(Hh / 128, Mm / 256), 512, 0, stream>>>(
      hs_h, hs_l, WqhT, WqlT, bq, qh, ql, Hh, Hh, Hh, Hh);
  gemm3_kernel<1><<<dim3(Hh / 128, Mm / 256), 512, 0, stream>>>(
      hs_h, hs_l, WkhT, WklT, bk, kh, kl, Hh, Hh, Hh, Hh);
  gemm3_kernel<2><<<dim3(Hh / 128, Mm / 256), 512, 0, stream>>>(
      hs_h, hs_l, WvhT, WvlT, bv, vT, nullptr, Hh, Hh, Hh, Mm);

  // 3) per batch: scores -> softmax -> context
  for (int b = 0; b < Bb; ++b) {
    const size_t tok = (size_t)b * Ss * Hh;
    gemm3_kernel<0><<<dim3(Ss / 128, Ss / 256), 512, 0, stream>>>(
        qh + tok, ql + tok, kh + tok, kl + tok, nullptr, Sbuf, nullptr, Hh, Hh, Hh, Ss);
    softmax_rows_kernel<<<dim3(Ss), 256, 0, stream>>>(Sbuf, Pbuf, Ss);
    gemm_nt_kernel<1, 0><<<dim3(Hh / BN, Ss / BM), 256, 0, stream>>>(
        Pbuf, nullptr, vT + (size_t)b * Ss, nullptr, nullptr,
        out + tok, nullptr, Ss, Ss, Mm, Hh);
  }
}